// Round 22
// baseline (295.488 us; speedup 1.0000x reference)
//
#include <hip/hip_runtime.h>
#include <hip/hip_bf16.h>
#include <string.h>

#define S3 110592  // 48^3
#define CDIM 96
#define EDIM 384
#define ZIN 14
#define YIN 22

typedef __attribute__((ext_vector_type(8))) short bf16x8;
typedef __attribute__((ext_vector_type(4))) float f32x4;
typedef unsigned short ushort_t;
typedef unsigned char uchar_t;

__device__ __forceinline__ ushort_t f2bf(float f) {
  __hip_bfloat16 h = __float2bfloat16(f);
  union { __hip_bfloat16 h; ushort_t u; } cv; cv.h = h; return cv.u;
}
__device__ __forceinline__ float bf2f(ushort_t u) {
  union { __hip_bfloat16 h; ushort_t u; } cv; cv.u = u; return __bfloat162float(cv.h);
}
// f32 -> fp8 e4m3 (OCP on gfx950), low byte of packed conversion
__device__ __forceinline__ uchar_t f2fp8(float f) {
  int r = __builtin_amdgcn_cvt_pk_fp8_f32(f, f, 0, false);
  return (uchar_t)(r & 0xff);
}
// tanh-form GELU in exp2/rcp form (log2e folded into constants)
__device__ __forceinline__ float gelu_fast(float v) {
  float t = v * v;
  float u = v * fmaf(-0.10294324f, t, -2.3022084f);
  float s = __builtin_amdgcn_exp2f(u);
  return v * __builtin_amdgcn_rcpf(1.f + s);
}

// ---------------------------------------------------------------- kinit: kpackB + kprep merged (independent prep, one launch)
__global__ void kinit(const float* __restrict__ dw_w,
                      const float* __restrict__ ln_w, const float* __restrict__ ln_b,
                      const float* __restrict__ w1, const float* __restrict__ b1,
                      const float* __restrict__ grn_b, const float* __restrict__ w2,
                      const float* __restrict__ b2,
                      ushort_t* __restrict__ Btab, ushort_t* __restrict__ w1p,
                      float* __restrict__ b1f, float* __restrict__ bias2) {
  int idx = blockIdx.x * 256 + threadIdx.x;
  // --- kpackB: SHIFTED Toeplitz B[k][n] = w[tz][ty][k-n-1], 8 outputs/thread, uint4 store
  {
    int base_i = idx * 8;  // grid sized exactly: base_i < 96*49*512
    int pos = base_i & 511; int t = (base_i >> 9) % 49; int c = base_i / (49 * 512);
    int lane = pos >> 3;
    int k0 = (lane >> 4) * 8, n = lane & 15;
    int tz = t / 7, ty = t % 7;
    const float* w = dw_w + c * 343 + tz * 49 + ty * 7;
    ushort_t tmp[8];
#pragma unroll
    for (int j = 0; j < 8; ++j) {
      int tx = k0 + j - n - 1;
      tmp[j] = (tx >= 0 && tx < 7) ? f2bf(w[tx]) : (ushort_t)0;
    }
    *(uint4*)&Btab[base_i] = *(uint4*)tmp;
  }
  // --- kprep: pack w1 (fold ln_w), b1f (fold ln_b), bias2 (fold grn_b via w2)
  if (idx < 24 * 3 * 64 * 8) {
    int j = idx & 7, lane = (idx >> 3) & 63, ks = (idx >> 9) % 3, nt = idx / 1536;
    int c = ks * 32 + (lane >> 4) * 8 + j;
    int e = nt * 16 + (lane & 15);
    w1p[idx] = f2bf(ln_w[c] * w1[c * EDIM + e]);
  }
  if (idx < EDIM) {
    float s = b1[idx];
    for (int c = 0; c < CDIM; ++c) s += ln_b[c] * w1[c * EDIM + idx];
    b1f[idx] = s;
  }
  if (idx < CDIM) {
    float s = b2[idx];
    for (int e = 0; e < EDIM; ++e) s += grn_b[e] * w2[e * CDIM + idx];
    bias2[idx] = s;
  }
}

// ---------------------------------------------------------------- depthwise conv MFMA compute (templated zl-half; all acc indices compile-time)
template<int HALF>
__device__ __forceinline__ void conv_ty_loop(const unsigned* tile, const ushort_t* Bt,
                                             int lane, int am, int xg, f32x4* acc) {
#pragma unroll 1
  for (int ty = 0; ty < 7; ++ty) {
    bf16x8 bfr[7];
#pragma unroll
    for (int tz = 0; tz < 7; ++tz)
      bfr[tz] = *(const bf16x8*)&Bt[(tz * 7 + ty) * 512 + lane * 8];  // L2-resident (XCD-affine)
    int rowbase = am + ty;
#pragma unroll
    for (int zl = 0; zl < 7; ++zl) {
      int row = (HALF * 7 + zl) * YIN + rowbase;
      int byteoff = (row << 7) + (xg ^ ((row & 7) << 4));
      bf16x8 af = *(const bf16x8*)((const char*)tile + byteoff);
#pragma unroll
      for (int tz = 0; tz < 7; ++tz) {
        int l = (HALF == 0) ? (zl - tz) : (zl + 6 - tz);
        if (l >= 0 && l < 7)  // compile-time after unroll
          acc[l] = __builtin_amdgcn_mfma_f32_16x16x32_bf16(af, bfr[tz], acc[l], 0, 0, 0);
      }
    }
  }
}

// ---------------------------------------------------------------- depthwise 7x7x7 conv on the MATRIX pipe
// 384 threads = 6 waves. Staging: register-prefetched (T14) — 2 batches of 10 clamped loads.
// XCD-affine bid (bid&7 = XCD): Btab slice + halos L2-resident.
__global__ __launch_bounds__(384, 6) void kconv(const float* __restrict__ x,
                                                const ushort_t* __restrict__ Btab,
                                                const float* __restrict__ dw_b,
                                                ushort_t* __restrict__ y) {
  __shared__ unsigned tile[ZIN * YIN * 32];
  int bid = blockIdx.x;                       // 3456 = 8 XCD * (12c * 2b * 6zt * 3yt)
  int xcd = bid & 7, wi = bid >> 3;           // wi in [0,432)
  int c = xcd * 12 + wi / 36;
  int rr_ = wi % 36;
  int b = rr_ / 18;
  int t_ = rr_ % 18;
  int zt = t_ / 3, yt = t_ % 3;
  int z0 = zt * 8, y0 = yt * 16;
  size_t base = (size_t)(b * 96 + c) * S3;
  int tid = threadIdx.x;

  // Phase A: zero edge pairs (pc 0,1,26..31) for all 308 rows
  for (int i = tid; i < 308 * 8; i += 384) {
    int row = i >> 3; int pe = i & 7;
    int pc = (pe < 2) ? pe : pe + 24;
    tile[(row << 5) + (pc ^ ((row & 7) << 2))] = 0u;
  }
  // Phase B: real pairs pc=2..25 (x = 2pc-4, 2pc-3 in [0,48)), register-prefetched
  {
    const float* xb = x + base;
#pragma unroll
    for (int hb = 0; hb < 2; ++hb) {
      float2 pv[10];
#pragma unroll
      for (int k = 0; k < 10; ++k) {
        int i = tid + (hb * 10 + k) * 384;
        i = (i < 7392) ? i : 7391;            // ragged tail -> duplicate benign
        int row = i / 24; int pc = 2 + (i - row * 24);
        int dz = row / YIN, dy = row - dz * YIN;
        int gz = z0 - 3 + dz, gy = y0 - 3 + dy;
        int cz = min(max(gz, 0), 47), cy = min(max(gy, 0), 47);
        pv[k] = *(const float2*)&xb[(size_t)cz * 2304 + cy * 48 + 2 * pc - 4];
      }
#pragma unroll
      for (int k = 0; k < 10; ++k) {
        int i = tid + (hb * 10 + k) * 384;
        i = (i < 7392) ? i : 7391;
        int row = i / 24; int pc = 2 + (i - row * 24);
        int dz = row / YIN, dy = row - dz * YIN;
        int gz = z0 - 3 + dz, gy = y0 - 3 + dy;
        bool ok = ((unsigned)gz < 48u) && ((unsigned)gy < 48u);
        float v0 = ok ? pv[k].x : 0.f;
        float v1 = ok ? pv[k].y : 0.f;
        tile[(row << 5) + (pc ^ ((row & 7) << 2))] = (unsigned)f2bf(v0) | ((unsigned)f2bf(v1) << 16);
      }
    }
  }
  __syncthreads();

  int w = tid >> 6;
  int X = w % 3, half = w / 3;
  int lane = tid & 63;
  int am = lane & 15, g = lane >> 4;
  int xg = X * 32 + g * 16;  // byte offset of k-window within row (before swizzle)

  f32x4 acc[7];
#pragma unroll
  for (int p = 0; p < 7; ++p) acc[p] = (f32x4){0.f, 0.f, 0.f, 0.f};

  const ushort_t* __restrict__ Bt = Btab + (size_t)c * 49 * 512;
  if (half == 0) conv_ty_loop<0>(tile, Bt, lane, am, xg, acc);
  else           conv_ty_loop<1>(tile, Bt, lane, am, xg, acc);

  float bv = dw_b[c];
  float* red = (float*)tile;
  int rcol = X * 16 + am;
  __syncthreads();  // all tile reads done -> reuse as f32 scratch
  if (half == 0) {
#pragma unroll
    for (int l = 1; l < 7; ++l)
#pragma unroll
      for (int r = 0; r < 4; ++r)
        red[(l - 1) * 800 + (g * 4 + r) * 50 + rcol] = acc[l][r];
  }
  __syncthreads();
  if (half == 0) {
    size_t zb = base + (size_t)z0 * 2304;
#pragma unroll
    for (int r = 0; r < 4; ++r)
      y[zb + (size_t)(y0 + g * 4 + r) * 48 + rcol] = f2bf(acc[0][r] + bv);
  } else {
#pragma unroll
    for (int l = 0; l < 7; ++l) {
      size_t zb = base + (size_t)(z0 + l + 1) * 2304;
#pragma unroll
      for (int r = 0; r < 4; ++r) {
        float v = acc[l][r] + bv;
        if (l < 6) v += red[l * 800 + (g * 4 + r) * 50 + rcol];
        y[zb + (size_t)(y0 + g * 4 + r) * 48 + rcol] = f2bf(v);
      }
    }
  }
}

// ---------------------------------------------------------------- pass 1: LN + GEMM1 + GELU -> sumsq + anorm (normalized y, bf16, [pos][96])
// bfg loaded IN-LOOP (frees ~36 VGPR) -> __launch_bounds__(512,6) admits 3 blocks/CU (24 waves).
__global__ __launch_bounds__(512, 6) void ksum(const ushort_t* __restrict__ y,
                                               const ushort_t* __restrict__ w1p,
                                               const float* __restrict__ b1f,
                                               float* __restrict__ sumsq,
                                               ushort_t* __restrict__ anorm) {
  __shared__ ushort_t Al[64 * 104];
  __shared__ float red_s[8][64], red_q[8][64];
  __shared__ float stat_mu[64], stat_rv[64];
  __shared__ float ssq_s[EDIM];
  int tid = threadIdx.x;
  int q = tid >> 6, lane = tid & 63;
  size_t pos0 = (size_t)blockIdx.x * 64;
  int b = (int)(pos0 / S3);
  int sp0 = (int)(pos0 % S3);

  float v[12];
  float s = 0.f, ss = 0.f;
  const ushort_t* yb = y + (size_t)b * 96 * S3 + sp0 + lane;
#pragma unroll
  for (int i = 0; i < 12; ++i) {
    float f = bf2f(yb[(size_t)(q * 12 + i) * S3]);
    v[i] = f; s += f; ss += f * f;
  }
  red_s[q][lane] = s; red_q[q][lane] = ss;
  __syncthreads();
  if (tid < 64) {
    float su = 0.f, sq = 0.f;
#pragma unroll
    for (int k = 0; k < 8; ++k) { su += red_s[k][tid]; sq += red_q[k][tid]; }
    float mu = su * (1.f / 96.f);
    float var = sq * (1.f / 96.f) - mu * mu;
    stat_mu[tid] = mu;
    stat_rv[tid] = rsqrtf(var + 1e-6f);
  }
  __syncthreads();
  {
    float mu = stat_mu[lane], rv = stat_rv[lane];
#pragma unroll
    for (int i4 = 0; i4 < 3; ++i4) {
      ushort_t u0 = f2bf((v[i4 * 4 + 0] - mu) * rv);
      ushort_t u1 = f2bf((v[i4 * 4 + 1] - mu) * rv);
      ushort_t u2 = f2bf((v[i4 * 4 + 2] - mu) * rv);
      ushort_t u3 = f2bf((v[i4 * 4 + 3] - mu) * rv);
      uint2 t; t.x = (unsigned)u0 | ((unsigned)u1 << 16); t.y = (unsigned)u2 | ((unsigned)u3 << 16);
      *(uint2*)&Al[lane * 104 + q * 12 + i4 * 4] = t;
    }
  }
  __syncthreads();

  // export normalized tile: [pos][96] bf16, 12 uint4 per position row
  {
    uint4* dst = (uint4*)(anorm + pos0 * 96);
    for (int i = tid; i < 64 * 12; i += 512) {
      int p = i / 12, j = i - p * 12;
      dst[p * 12 + j] = *(const uint4*)&Al[p * 104 + j * 8];
    }
  }

  f32x4 acc[4][3];
#pragma unroll
  for (int mt = 0; mt < 4; ++mt)
#pragma unroll
    for (int ntl = 0; ntl < 3; ++ntl) acc[mt][ntl] = (f32x4){0.f, 0.f, 0.f, 0.f};

  int row = lane & 15, g = lane >> 4;
#pragma unroll
  for (int ks = 0; ks < 3; ++ks) {
    bf16x8 af[4];
    int colb = ks * 32 + g * 8;
#pragma unroll
    for (int mt = 0; mt < 4; ++mt)
      af[mt] = *(const bf16x8*)&Al[(mt * 16 + row) * 104 + colb];
#pragma unroll
    for (int ntl = 0; ntl < 3; ++ntl) {
      bf16x8 bfg = *(const bf16x8*)&w1p[(size_t)(((q * 3 + ntl) * 3 + ks) * 64 + lane) * 8];
#pragma unroll
      for (int mt = 0; mt < 4; ++mt)
        acc[mt][ntl] = __builtin_amdgcn_mfma_f32_16x16x32_bf16(af[mt], bfg, acc[mt][ntl], 0, 0, 0);
    }
  }

#pragma unroll
  for (int ntl = 0; ntl < 3; ++ntl) {
    int e = q * 48 + ntl * 16 + row;
    float bb = b1f[e];
    float ssq = 0.f;
#pragma unroll
    for (int mt = 0; mt < 4; ++mt) {
#pragma unroll
      for (int r = 0; r < 4; ++r) {
        float gel = gelu_fast(acc[mt][ntl][r] + bb);
        ssq += gel * gel;
      }
    }
    ssq += __shfl_xor(ssq, 16, 64);
    ssq += __shfl_xor(ssq, 32, 64);
    if (g == 0) ssq_s[e] = ssq;
  }
  __syncthreads();
  if (tid < EDIM) atomicAdd(&sumsq[b * EDIM + tid], ssq_s[tid]);
}

// ---------------------------------------------------------------- kpackw2 (kscale folded in): per-batch GRN scale + fp8 pack of scale*w2
__global__ void kpackw2(const float* __restrict__ sumsq, const float* __restrict__ grn_w,
                        const float* __restrict__ w2, uchar_t* __restrict__ w2s) {
  __shared__ float redw[4];
  __shared__ float mean_s;
  int tid = threadIdx.x;
  int idx = blockIdx.x * 256 + tid;  // exactly 9216
  int b = idx / 4608;
  // block-local GRN mean over 384 channels
  float p = sqrtf(sumsq[b * EDIM + tid]);
  if (tid < 128) p += sqrtf(sumsq[b * EDIM + 256 + tid]);
#pragma unroll
  for (int off = 1; off <= 32; off <<= 1) p += __shfl_xor(p, off, 64);
  if ((tid & 63) == 0) redw[tid >> 6] = p;
  __syncthreads();
  if (tid == 0) mean_s = (redw[0] + redw[1] + redw[2] + redw[3]) * (1.f / EDIM);
  __syncthreads();
  float inv = 1.f / (mean_s + 1e-6f);

  int lane = idx & 63;
  int ks = (idx >> 6) % 12;
  int nt = ((idx >> 6) / 12) % 6;
  int cc = nt * 16 + (lane & 15);
  float sw[8];
#pragma unroll
  for (int j = 0; j < 8; ++j) {
    int e = ks * 32 + (lane >> 4) * 8 + j;
    float sc = grn_w[e] * (sqrtf(sumsq[b * EDIM + e]) * inv) + 1.f;
    sw[j] = sc * w2[e * CDIM + cc];
  }
  unsigned r0 = (unsigned)__builtin_amdgcn_cvt_pk_fp8_f32(sw[0], sw[1], 0, false);
  r0 = (unsigned)__builtin_amdgcn_cvt_pk_fp8_f32(sw[2], sw[3], (int)r0, true);
  unsigned r1 = (unsigned)__builtin_amdgcn_cvt_pk_fp8_f32(sw[4], sw[5], 0, false);
  r1 = (unsigned)__builtin_amdgcn_cvt_pk_fp8_f32(sw[6], sw[7], (int)r1, true);
  *(uint2*)&w2s[(size_t)((b * 72 + nt * 12 + ks) * 64 + lane) * 8] = make_uint2(r0, r1);
}

// ---------------------------------------------------------------- pass 2 FUSED (64 pos/block):
// GEMM1(anorm, bf16) -> GELU -> fp8 LDS h-tile [64][400] -> GEMM2(fp8) -> +x, direct store.
// x residual prefetched at kernel start (T14): HBM latency hidden under GEMM1+GELU+GEMM2.
__global__ __launch_bounds__(512, 6) void kfused(const ushort_t* __restrict__ anorm,
                                                 const ushort_t* __restrict__ w1p,
                                                 const float* __restrict__ b1f,
                                                 const uchar_t* __restrict__ w2s,
                                                 const float* __restrict__ bias2,
                                                 const float* __restrict__ x,
                                                 float* __restrict__ out) {
  __shared__ __align__(16) uchar_t htile[64 * 400];

  int tid = threadIdx.x;
  int q = tid >> 6, lane = tid & 63;
  size_t pos0 = (size_t)blockIdx.x * 64;
  int b = (int)(pos0 / S3);
  int sp0 = (int)(pos0 % S3);
  int row = lane & 15, g = lane >> 4;
  int mt2 = q & 3, nh = q >> 2;

  // ---- early x prefetch + bias2 (consumed after GEMM2; latency hidden under compute)
  f32x4 xv[3];
  float bb2[3];
#pragma unroll
  for (int ntl = 0; ntl < 3; ++ntl) {
    int cc = (nh * 3 + ntl) * 16 + row;
    xv[ntl] = *(const f32x4*)&x[(size_t)(b * 96 + cc) * S3 + sp0 + mt2 * 16 + g * 4];
    bb2[ntl] = bias2[cc];
  }

  // ---- GEMM1: A direct from anorm (bf16), wave q -> e-range [q*48, +48)
  f32x4 acc[4][3];
#pragma unroll
  for (int mt = 0; mt < 4; ++mt)
#pragma unroll
    for (int ntl = 0; ntl < 3; ++ntl) acc[mt][ntl] = (f32x4){0.f, 0.f, 0.f, 0.f};

  const ushort_t* ab = anorm + pos0 * 96;
#pragma unroll
  for (int ks = 0; ks < 3; ++ks) {
    int colb = ks * 32 + g * 8;
    bf16x8 af[4];
#pragma unroll
    for (int mt = 0; mt < 4; ++mt)
      af[mt] = *(const bf16x8*)&ab[(mt * 16 + row) * 96 + colb];
#pragma unroll
    for (int ntl = 0; ntl < 3; ++ntl) {
      bf16x8 bfg = *(const bf16x8*)&w1p[(size_t)(((q * 3 + ntl) * 3 + ks) * 64 + lane) * 8];
#pragma unroll
      for (int mt = 0; mt < 4; ++mt)
        acc[mt][ntl] = __builtin_amdgcn_mfma_f32_16x16x32_bf16(af[mt], bfg, acc[mt][ntl], 0, 0, 0);
    }
  }

  // ---- GELU -> fp8 LDS h-tile [p][e], row stride 400 B
#pragma unroll
  for (int ntl = 0; ntl < 3; ++ntl) {
    int e = q * 48 + ntl * 16 + row;
    float bb = b1f[e];
#pragma unroll
    for (int mt = 0; mt < 4; ++mt) {
#pragma unroll
      for (int r = 0; r < 4; ++r) {
        float gel = gelu_fast(acc[mt][ntl][r] + bb);
        htile[(mt * 16 + g * 4 + r) * 400 + e] = f2fp8(gel);
      }
    }
  }
  __syncthreads();

  // ---- GEMM2 (fp8): wave q -> m-tile (q&3), c-half (q>>2)
  f32x4 acc2[3];
#pragma unroll
  for (int ntl = 0; ntl < 3; ++ntl) acc2[ntl] = (f32x4){0.f, 0.f, 0.f, 0.f};
  const uchar_t* w2b = w2s + (size_t)b * 36864;
  const uchar_t* arow = &htile[(mt2 * 16 + row) * 400];
#pragma unroll
  for (int ks = 0; ks < 12; ++ks) {
    long af8 = *(const long*)&arow[g * 8 + ks * 32];
#pragma unroll
    for (int ntl = 0; ntl < 3; ++ntl) {
      int nt = nh * 3 + ntl;
      long bf8 = *(const long*)&w2b[(size_t)((nt * 12 + ks) * 64 + lane) * 8];
      acc2[ntl] = __builtin_amdgcn_mfma_f32_16x16x32_fp8_fp8(af8, bf8, acc2[ntl], 0, 0, 0);
    }
  }

  // ---- direct store: out = acc2 + bias2 + x (position-contiguous float4 per lane)
#pragma unroll
  for (int ntl = 0; ntl < 3; ++ntl) {
    int cc = (nh * 3 + ntl) * 16 + row;
    f32x4 ov;
#pragma unroll
    for (int r = 0; r < 4; ++r) ov[r] = acc2[ntl][r] + bb2[ntl] + xv[ntl][r];
    *(f32x4*)&out[(size_t)(b * 96 + cc) * S3 + sp0 + mt2 * 16 + g * 4] = ov;
  }
}

// ----------------------------------------------------------------
extern "C" void kernel_launch(void* const* d_in, const int* in_sizes, int n_in,
                              void* d_out, int out_size, void* d_ws, size_t ws_size,
                              hipStream_t stream) {
  const float* x     = (const float*)d_in[0];
  const float* dw_w  = (const float*)d_in[1];
  const float* dw_b  = (const float*)d_in[2];
  const float* ln_w  = (const float*)d_in[3];
  const float* ln_b  = (const float*)d_in[4];
  const float* w1    = (const float*)d_in[5];
  const float* b1    = (const float*)d_in[6];
  const float* grn_w = (const float*)d_in[7];
  const float* grn_b = (const float*)d_in[8];
  const float* w2    = (const float*)d_in[9];
  const float* b2    = (const float*)d_in[10];
  float* out = (float*)d_out;

  char* ws = (char*)d_ws;
  size_t off = 0;
  auto alloc = [&](size_t bytes) -> void* {
    void* p = ws + off;
    off = (off + bytes + 511) & ~(size_t)511;
    return p;
  };
  ushort_t* y     = (ushort_t*)alloc((size_t)2 * 96 * S3 * 2);       // 42.5 MB bf16 conv out
  ushort_t* anorm = (ushort_t*)alloc((size_t)221184 * 96 * 2);       // 42.5 MB normalized bf16
  ushort_t* w1p   = (ushort_t*)alloc(36864 * 2);
  uchar_t* w2s    = (uchar_t*)alloc((size_t)2 * 36864);              // fp8 scale-folded w2
  ushort_t* Btab  = (ushort_t*)alloc((size_t)96 * 49 * 512 * 2);     // 4.8 MB Toeplitz B-frags
  float* b1f      = (float*)alloc(EDIM * 4);
  float* bias2    = (float*)alloc(CDIM * 4);
  float* sumsq    = (float*)alloc(2 * EDIM * 4);

  hipMemsetAsync(sumsq, 0, 2 * EDIM * 4, stream);
  kinit<<<1176, 256, 0, stream>>>(dw_w, ln_w, ln_b, w1, b1, grn_b, w2, b2, Btab, w1p, b1f, bias2);
  kconv<<<3456, 384, 0, stream>>>(x, Btab, dw_b, y);
  ksum<<<3456, 512, 0, stream>>>(y, w1p, b1f, sumsq, anorm);
  kpackw2<<<36, 256, 0, stream>>>(sumsq, grn_w, w2, w2s);
  kfused<<<3456, 512, 0, stream>>>(anorm, w1p, b1f, w2s, bias2, x, out);
}

// Round 23
// 283.539 us; speedup vs baseline: 1.0421x; 1.0421x over previous
//
#include <hip/hip_runtime.h>
#include <hip/hip_bf16.h>
#include <string.h>

#define S3 110592  // 48^3
#define CDIM 96
#define EDIM 384
#define ZIN 14
#define YIN 22

typedef __attribute__((ext_vector_type(8))) short bf16x8;
typedef __attribute__((ext_vector_type(4))) float f32x4;
typedef unsigned short ushort_t;
typedef unsigned char uchar_t;

__device__ __forceinline__ ushort_t f2bf(float f) {
  __hip_bfloat16 h = __float2bfloat16(f);
  union { __hip_bfloat16 h; ushort_t u; } cv; cv.h = h; return cv.u;
}
__device__ __forceinline__ float bf2f(ushort_t u) {
  union { __hip_bfloat16 h; ushort_t u; } cv; cv.u = u; return __bfloat162float(cv.h);
}
// f32 -> fp8 e4m3 (OCP on gfx950), low byte of packed conversion
__device__ __forceinline__ uchar_t f2fp8(float f) {
  int r = __builtin_amdgcn_cvt_pk_fp8_f32(f, f, 0, false);
  return (uchar_t)(r & 0xff);
}
// tanh-form GELU in exp2/rcp form (log2e folded into constants)
__device__ __forceinline__ float gelu_fast(float v) {
  float t = v * v;
  float u = v * fmaf(-0.10294324f, t, -2.3022084f);
  float s = __builtin_amdgcn_exp2f(u);
  return v * __builtin_amdgcn_rcpf(1.f + s);
}

// ---------------------------------------------------------------- kinit: kpackB + kprep merged (independent prep, one launch)
__global__ void kinit(const float* __restrict__ dw_w,
                      const float* __restrict__ ln_w, const float* __restrict__ ln_b,
                      const float* __restrict__ w1, const float* __restrict__ b1,
                      const float* __restrict__ grn_b, const float* __restrict__ w2,
                      const float* __restrict__ b2,
                      ushort_t* __restrict__ Btab, ushort_t* __restrict__ w1p,
                      float* __restrict__ b1f, float* __restrict__ bias2) {
  int idx = blockIdx.x * 256 + threadIdx.x;
  // --- kpackB: SHIFTED Toeplitz B[k][n] = w[tz][ty][k-n-1], 8 outputs/thread, uint4 store
  {
    int base_i = idx * 8;  // grid sized exactly: base_i < 96*49*512
    int pos = base_i & 511; int t = (base_i >> 9) % 49; int c = base_i / (49 * 512);
    int lane = pos >> 3;
    int k0 = (lane >> 4) * 8, n = lane & 15;
    int tz = t / 7, ty = t % 7;
    const float* w = dw_w + c * 343 + tz * 49 + ty * 7;
    ushort_t tmp[8];
#pragma unroll
    for (int j = 0; j < 8; ++j) {
      int tx = k0 + j - n - 1;
      tmp[j] = (tx >= 0 && tx < 7) ? f2bf(w[tx]) : (ushort_t)0;
    }
    *(uint4*)&Btab[base_i] = *(uint4*)tmp;
  }
  // --- kprep: pack w1 (fold ln_w), b1f (fold ln_b), bias2 (fold grn_b via w2)
  if (idx < 24 * 3 * 64 * 8) {
    int j = idx & 7, lane = (idx >> 3) & 63, ks = (idx >> 9) % 3, nt = idx / 1536;
    int c = ks * 32 + (lane >> 4) * 8 + j;
    int e = nt * 16 + (lane & 15);
    w1p[idx] = f2bf(ln_w[c] * w1[c * EDIM + e]);
  }
  if (idx < EDIM) {
    float s = b1[idx];
    for (int c = 0; c < CDIM; ++c) s += ln_b[c] * w1[c * EDIM + idx];
    b1f[idx] = s;
  }
  if (idx < CDIM) {
    float s = b2[idx];
    for (int e = 0; e < EDIM; ++e) s += grn_b[e] * w2[e * CDIM + idx];
    bias2[idx] = s;
  }
}

// ---------------------------------------------------------------- depthwise conv MFMA compute (templated zl-half; all acc indices compile-time)
template<int HALF>
__device__ __forceinline__ void conv_ty_loop(const unsigned* tile, const ushort_t* Bt,
                                             int lane, int am, int xg, f32x4* acc) {
#pragma unroll 1
  for (int ty = 0; ty < 7; ++ty) {
    bf16x8 bfr[7];
#pragma unroll
    for (int tz = 0; tz < 7; ++tz)
      bfr[tz] = *(const bf16x8*)&Bt[(tz * 7 + ty) * 512 + lane * 8];  // L2-resident (XCD-affine)
    int rowbase = am + ty;
#pragma unroll
    for (int zl = 0; zl < 7; ++zl) {
      int row = (HALF * 7 + zl) * YIN + rowbase;
      int byteoff = (row << 7) + (xg ^ ((row & 7) << 4));
      bf16x8 af = *(const bf16x8*)((const char*)tile + byteoff);
#pragma unroll
      for (int tz = 0; tz < 7; ++tz) {
        int l = (HALF == 0) ? (zl - tz) : (zl + 6 - tz);
        if (l >= 0 && l < 7)  // compile-time after unroll
          acc[l] = __builtin_amdgcn_mfma_f32_16x16x32_bf16(af, bfr[tz], acc[l], 0, 0, 0);
      }
    }
  }
}

// ---------------------------------------------------------------- depthwise 7x7x7 conv on the MATRIX pipe
// 384 threads = 6 waves. Staging: register-prefetched (T14) — 2 batches of 10 clamped loads.
// XCD-affine bid (bid&7 = XCD): Btab slice + halos L2-resident.
__global__ __launch_bounds__(384, 6) void kconv(const float* __restrict__ x,
                                                const ushort_t* __restrict__ Btab,
                                                const float* __restrict__ dw_b,
                                                ushort_t* __restrict__ y) {
  __shared__ unsigned tile[ZIN * YIN * 32];
  int bid = blockIdx.x;                       // 3456 = 8 XCD * (12c * 2b * 6zt * 3yt)
  int xcd = bid & 7, wi = bid >> 3;           // wi in [0,432)
  int c = xcd * 12 + wi / 36;
  int rr_ = wi % 36;
  int b = rr_ / 18;
  int t_ = rr_ % 18;
  int zt = t_ / 3, yt = t_ % 3;
  int z0 = zt * 8, y0 = yt * 16;
  size_t base = (size_t)(b * 96 + c) * S3;
  int tid = threadIdx.x;

  // Phase A: zero edge pairs (pc 0,1,26..31) for all 308 rows
  for (int i = tid; i < 308 * 8; i += 384) {
    int row = i >> 3; int pe = i & 7;
    int pc = (pe < 2) ? pe : pe + 24;
    tile[(row << 5) + (pc ^ ((row & 7) << 2))] = 0u;
  }
  // Phase B: real pairs pc=2..25 (x = 2pc-4, 2pc-3 in [0,48)), register-prefetched
  {
    const float* xb = x + base;
#pragma unroll
    for (int hb = 0; hb < 2; ++hb) {
      float2 pv[10];
#pragma unroll
      for (int k = 0; k < 10; ++k) {
        int i = tid + (hb * 10 + k) * 384;
        i = (i < 7392) ? i : 7391;            // ragged tail -> duplicate benign
        int row = i / 24; int pc = 2 + (i - row * 24);
        int dz = row / YIN, dy = row - dz * YIN;
        int gz = z0 - 3 + dz, gy = y0 - 3 + dy;
        int cz = min(max(gz, 0), 47), cy = min(max(gy, 0), 47);
        pv[k] = *(const float2*)&xb[(size_t)cz * 2304 + cy * 48 + 2 * pc - 4];
      }
#pragma unroll
      for (int k = 0; k < 10; ++k) {
        int i = tid + (hb * 10 + k) * 384;
        i = (i < 7392) ? i : 7391;
        int row = i / 24; int pc = 2 + (i - row * 24);
        int dz = row / YIN, dy = row - dz * YIN;
        int gz = z0 - 3 + dz, gy = y0 - 3 + dy;
        bool ok = ((unsigned)gz < 48u) && ((unsigned)gy < 48u);
        float v0 = ok ? pv[k].x : 0.f;
        float v1 = ok ? pv[k].y : 0.f;
        tile[(row << 5) + (pc ^ ((row & 7) << 2))] = (unsigned)f2bf(v0) | ((unsigned)f2bf(v1) << 16);
      }
    }
  }
  __syncthreads();

  int w = tid >> 6;
  int X = w % 3, half = w / 3;
  int lane = tid & 63;
  int am = lane & 15, g = lane >> 4;
  int xg = X * 32 + g * 16;  // byte offset of k-window within row (before swizzle)

  f32x4 acc[7];
#pragma unroll
  for (int p = 0; p < 7; ++p) acc[p] = (f32x4){0.f, 0.f, 0.f, 0.f};

  const ushort_t* __restrict__ Bt = Btab + (size_t)c * 49 * 512;
  if (half == 0) conv_ty_loop<0>(tile, Bt, lane, am, xg, acc);
  else           conv_ty_loop<1>(tile, Bt, lane, am, xg, acc);

  float bv = dw_b[c];
  float* red = (float*)tile;
  int rcol = X * 16 + am;
  __syncthreads();  // all tile reads done -> reuse as f32 scratch
  if (half == 0) {
#pragma unroll
    for (int l = 1; l < 7; ++l)
#pragma unroll
      for (int r = 0; r < 4; ++r)
        red[(l - 1) * 800 + (g * 4 + r) * 50 + rcol] = acc[l][r];
  }
  __syncthreads();
  if (half == 0) {
    size_t zb = base + (size_t)z0 * 2304;
#pragma unroll
    for (int r = 0; r < 4; ++r)
      y[zb + (size_t)(y0 + g * 4 + r) * 48 + rcol] = f2bf(acc[0][r] + bv);
  } else {
#pragma unroll
    for (int l = 0; l < 7; ++l) {
      size_t zb = base + (size_t)(z0 + l + 1) * 2304;
#pragma unroll
      for (int r = 0; r < 4; ++r) {
        float v = acc[l][r] + bv;
        if (l < 6) v += red[l * 800 + (g * 4 + r) * 50 + rcol];
        y[zb + (size_t)(y0 + g * 4 + r) * 48 + rcol] = f2bf(v);
      }
    }
  }
}

// ---------------------------------------------------------------- pass 1: LN + GEMM1 + GELU -> sumsq + anorm (normalized y, bf16, [pos][96])
__global__ __launch_bounds__(512, 4) void ksum(const ushort_t* __restrict__ y,
                                               const ushort_t* __restrict__ w1p,
                                               const float* __restrict__ b1f,
                                               float* __restrict__ sumsq,
                                               ushort_t* __restrict__ anorm) {
  __shared__ ushort_t Al[64 * 104];
  __shared__ float red_s[8][64], red_q[8][64];
  __shared__ float stat_mu[64], stat_rv[64];
  __shared__ float ssq_s[EDIM];
  int tid = threadIdx.x;
  int q = tid >> 6, lane = tid & 63;
  size_t pos0 = (size_t)blockIdx.x * 64;
  int b = (int)(pos0 / S3);
  int sp0 = (int)(pos0 % S3);

  bf16x8 bfg[3][3];
#pragma unroll
  for (int ntl = 0; ntl < 3; ++ntl)
#pragma unroll
    for (int ks = 0; ks < 3; ++ks)
      bfg[ntl][ks] = *(const bf16x8*)&w1p[(size_t)(((q * 3 + ntl) * 3 + ks) * 64 + lane) * 8];

  float v[12];
  float s = 0.f, ss = 0.f;
  const ushort_t* yb = y + (size_t)b * 96 * S3 + sp0 + lane;
#pragma unroll
  for (int i = 0; i < 12; ++i) {
    float f = bf2f(yb[(size_t)(q * 12 + i) * S3]);
    v[i] = f; s += f; ss += f * f;
  }
  red_s[q][lane] = s; red_q[q][lane] = ss;
  __syncthreads();
  if (tid < 64) {
    float su = 0.f, sq = 0.f;
#pragma unroll
    for (int k = 0; k < 8; ++k) { su += red_s[k][tid]; sq += red_q[k][tid]; }
    float mu = su * (1.f / 96.f);
    float var = sq * (1.f / 96.f) - mu * mu;
    stat_mu[tid] = mu;
    stat_rv[tid] = rsqrtf(var + 1e-6f);
  }
  __syncthreads();
  {
    float mu = stat_mu[lane], rv = stat_rv[lane];
#pragma unroll
    for (int i4 = 0; i4 < 3; ++i4) {
      ushort_t u0 = f2bf((v[i4 * 4 + 0] - mu) * rv);
      ushort_t u1 = f2bf((v[i4 * 4 + 1] - mu) * rv);
      ushort_t u2 = f2bf((v[i4 * 4 + 2] - mu) * rv);
      ushort_t u3 = f2bf((v[i4 * 4 + 3] - mu) * rv);
      uint2 t; t.x = (unsigned)u0 | ((unsigned)u1 << 16); t.y = (unsigned)u2 | ((unsigned)u3 << 16);
      *(uint2*)&Al[lane * 104 + q * 12 + i4 * 4] = t;
    }
  }
  __syncthreads();

  // export normalized tile: [pos][96] bf16, 12 uint4 per position row
  {
    uint4* dst = (uint4*)(anorm + pos0 * 96);
    for (int i = tid; i < 64 * 12; i += 512) {
      int p = i / 12, j = i - p * 12;
      dst[p * 12 + j] = *(const uint4*)&Al[p * 104 + j * 8];
    }
  }

  f32x4 acc[4][3];
#pragma unroll
  for (int mt = 0; mt < 4; ++mt)
#pragma unroll
    for (int ntl = 0; ntl < 3; ++ntl) acc[mt][ntl] = (f32x4){0.f, 0.f, 0.f, 0.f};

  int row = lane & 15, g = lane >> 4;
#pragma unroll
  for (int ks = 0; ks < 3; ++ks) {
    bf16x8 af[4];
    int colb = ks * 32 + g * 8;
#pragma unroll
    for (int mt = 0; mt < 4; ++mt)
      af[mt] = *(const bf16x8*)&Al[(mt * 16 + row) * 104 + colb];
#pragma unroll
    for (int ntl = 0; ntl < 3; ++ntl) {
#pragma unroll
      for (int mt = 0; mt < 4; ++mt)
        acc[mt][ntl] = __builtin_amdgcn_mfma_f32_16x16x32_bf16(af[mt], bfg[ntl][ks], acc[mt][ntl], 0, 0, 0);
    }
  }

#pragma unroll
  for (int ntl = 0; ntl < 3; ++ntl) {
    int e = q * 48 + ntl * 16 + row;
    float bb = b1f[e];
    float ssq = 0.f;
#pragma unroll
    for (int mt = 0; mt < 4; ++mt) {
#pragma unroll
      for (int r = 0; r < 4; ++r) {
        float gel = gelu_fast(acc[mt][ntl][r] + bb);
        ssq += gel * gel;
      }
    }
    ssq += __shfl_xor(ssq, 16, 64);
    ssq += __shfl_xor(ssq, 32, 64);
    if (g == 0) ssq_s[e] = ssq;
  }
  __syncthreads();
  if (tid < EDIM) atomicAdd(&sumsq[b * EDIM + tid], ssq_s[tid]);
}

// ---------------------------------------------------------------- kpackw2 (kscale folded in): per-batch GRN scale + fp8 pack of scale*w2
__global__ void kpackw2(const float* __restrict__ sumsq, const float* __restrict__ grn_w,
                        const float* __restrict__ w2, uchar_t* __restrict__ w2s) {
  __shared__ float redw[4];
  __shared__ float mean_s;
  int tid = threadIdx.x;
  int idx = blockIdx.x * 256 + tid;  // exactly 9216
  int b = idx / 4608;
  // block-local GRN mean over 384 channels
  float p = sqrtf(sumsq[b * EDIM + tid]);
  if (tid < 128) p += sqrtf(sumsq[b * EDIM + 256 + tid]);
#pragma unroll
  for (int off = 1; off <= 32; off <<= 1) p += __shfl_xor(p, off, 64);
  if ((tid & 63) == 0) redw[tid >> 6] = p;
  __syncthreads();
  if (tid == 0) mean_s = (redw[0] + redw[1] + redw[2] + redw[3]) * (1.f / EDIM);
  __syncthreads();
  float inv = 1.f / (mean_s + 1e-6f);

  int lane = idx & 63;
  int ks = (idx >> 6) % 12;
  int nt = ((idx >> 6) / 12) % 6;
  int cc = nt * 16 + (lane & 15);
  float sw[8];
#pragma unroll
  for (int j = 0; j < 8; ++j) {
    int e = ks * 32 + (lane >> 4) * 8 + j;
    float sc = grn_w[e] * (sqrtf(sumsq[b * EDIM + e]) * inv) + 1.f;
    sw[j] = sc * w2[e * CDIM + cc];
  }
  unsigned r0 = (unsigned)__builtin_amdgcn_cvt_pk_fp8_f32(sw[0], sw[1], 0, false);
  r0 = (unsigned)__builtin_amdgcn_cvt_pk_fp8_f32(sw[2], sw[3], (int)r0, true);
  unsigned r1 = (unsigned)__builtin_amdgcn_cvt_pk_fp8_f32(sw[4], sw[5], 0, false);
  r1 = (unsigned)__builtin_amdgcn_cvt_pk_fp8_f32(sw[6], sw[7], (int)r1, true);
  *(uint2*)&w2s[(size_t)((b * 72 + nt * 12 + ks) * 64 + lane) * 8] = make_uint2(r0, r1);
}

// ---------------------------------------------------------------- pass 2 FUSED (64 pos/block):
// GEMM1(anorm, bf16) -> GELU -> fp8 LDS h-tile [64][400] -> GEMM2(fp8) -> +x, direct store.
// x residual prefetched at kernel start (T14): HBM latency hidden under GEMM1+GELU+GEMM2.
__global__ __launch_bounds__(512, 6) void kfused(const ushort_t* __restrict__ anorm,
                                                 const ushort_t* __restrict__ w1p,
                                                 const float* __restrict__ b1f,
                                                 const uchar_t* __restrict__ w2s,
                                                 const float* __restrict__ bias2,
                                                 const float* __restrict__ x,
                                                 float* __restrict__ out) {
  __shared__ __align__(16) uchar_t htile[64 * 400];

  int tid = threadIdx.x;
  int q = tid >> 6, lane = tid & 63;
  size_t pos0 = (size_t)blockIdx.x * 64;
  int b = (int)(pos0 / S3);
  int sp0 = (int)(pos0 % S3);
  int row = lane & 15, g = lane >> 4;
  int mt2 = q & 3, nh = q >> 2;

  // ---- early x prefetch + bias2 (consumed after GEMM2; latency hidden under compute)
  f32x4 xv[3];
  float bb2[3];
#pragma unroll
  for (int ntl = 0; ntl < 3; ++ntl) {
    int cc = (nh * 3 + ntl) * 16 + row;
    xv[ntl] = *(const f32x4*)&x[(size_t)(b * 96 + cc) * S3 + sp0 + mt2 * 16 + g * 4];
    bb2[ntl] = bias2[cc];
  }

  // ---- GEMM1: A direct from anorm (bf16), wave q -> e-range [q*48, +48)
  f32x4 acc[4][3];
#pragma unroll
  for (int mt = 0; mt < 4; ++mt)
#pragma unroll
    for (int ntl = 0; ntl < 3; ++ntl) acc[mt][ntl] = (f32x4){0.f, 0.f, 0.f, 0.f};

  const ushort_t* ab = anorm + pos0 * 96;
#pragma unroll
  for (int ks = 0; ks < 3; ++ks) {
    int colb = ks * 32 + g * 8;
    bf16x8 af[4];
#pragma unroll
    for (int mt = 0; mt < 4; ++mt)
      af[mt] = *(const bf16x8*)&ab[(mt * 16 + row) * 96 + colb];
#pragma unroll
    for (int ntl = 0; ntl < 3; ++ntl) {
      bf16x8 bfg = *(const bf16x8*)&w1p[(size_t)(((q * 3 + ntl) * 3 + ks) * 64 + lane) * 8];
#pragma unroll
      for (int mt = 0; mt < 4; ++mt)
        acc[mt][ntl] = __builtin_amdgcn_mfma_f32_16x16x32_bf16(af[mt], bfg, acc[mt][ntl], 0, 0, 0);
    }
  }

  // ---- GELU -> fp8 LDS h-tile [p][e], row stride 400 B
#pragma unroll
  for (int ntl = 0; ntl < 3; ++ntl) {
    int e = q * 48 + ntl * 16 + row;
    float bb = b1f[e];
#pragma unroll
    for (int mt = 0; mt < 4; ++mt) {
#pragma unroll
      for (int r = 0; r < 4; ++r) {
        float gel = gelu_fast(acc[mt][ntl][r] + bb);
        htile[(mt * 16 + g * 4 + r) * 400 + e] = f2fp8(gel);
      }
    }
  }
  __syncthreads();

  // ---- GEMM2 (fp8): wave q -> m-tile (q&3), c-half (q>>2)
  f32x4 acc2[3];
#pragma unroll
  for (int ntl = 0; ntl < 3; ++ntl) acc2[ntl] = (f32x4){0.f, 0.f, 0.f, 0.f};
  const uchar_t* w2b = w2s + (size_t)b * 36864;
  const uchar_t* arow = &htile[(mt2 * 16 + row) * 400];
#pragma unroll
  for (int ks = 0; ks < 12; ++ks) {
    long af8 = *(const long*)&arow[g * 8 + ks * 32];
#pragma unroll
    for (int ntl = 0; ntl < 3; ++ntl) {
      int nt = nh * 3 + ntl;
      long bf8 = *(const long*)&w2b[(size_t)((nt * 12 + ks) * 64 + lane) * 8];
      acc2[ntl] = __builtin_amdgcn_mfma_f32_16x16x32_fp8_fp8(af8, bf8, acc2[ntl], 0, 0, 0);
    }
  }

  // ---- direct store: out = acc2 + bias2 + x (position-contiguous float4 per lane)
#pragma unroll
  for (int ntl = 0; ntl < 3; ++ntl) {
    int cc = (nh * 3 + ntl) * 16 + row;
    f32x4 ov;
#pragma unroll
    for (int r = 0; r < 4; ++r) ov[r] = acc2[ntl][r] + bb2[ntl] + xv[ntl][r];
    *(f32x4*)&out[(size_t)(b * 96 + cc) * S3 + sp0 + mt2 * 16 + g * 4] = ov;
  }
}

// ----------------------------------------------------------------
extern "C" void kernel_launch(void* const* d_in, const int* in_sizes, int n_in,
                              void* d_out, int out_size, void* d_ws, size_t ws_size,
                              hipStream_t stream) {
  const float* x     = (const float*)d_in[0];
  const float* dw_w  = (const float*)d_in[1];
  const float* dw_b  = (const float*)d_in[2];
  const float* ln_w  = (const float*)d_in[3];
  const float* ln_b  = (const float*)d_in[4];
  const float* w1    = (const float*)d_in[5];
  const float* b1    = (const float*)d_in[6];
  const float* grn_w = (const float*)d_in[7];
  const float* grn_b = (const float*)d_in[8];
  const float* w2    = (const float*)d_in[9];
  const float* b2    = (const float*)d_in[10];
  float* out = (float*)d_out;

  char* ws = (char*)d_ws;
  size_t off = 0;
  auto alloc = [&](size_t bytes) -> void* {
    void* p = ws + off;
    off = (off + bytes + 511) & ~(size_t)511;
    return p;
  };
  ushort_t* y     = (ushort_t*)alloc((size_t)2 * 96 * S3 * 2);       // 42.5 MB bf16 conv out
  ushort_t* anorm = (ushort_t*)alloc((size_t)221184 * 96 * 2);       // 42.5 MB normalized bf16
  ushort_t* w1p   = (ushort_t*)alloc(36864 * 2);
  uchar_t* w2s    = (uchar_t*)alloc((size_t)2 * 36864);              // fp8 scale-folded w2
  ushort_t* Btab  = (ushort_t*)alloc((size_t)96 * 49 * 512 * 2);     // 4.8 MB Toeplitz B-frags
  float* b1f      = (float*)alloc(EDIM * 4);
  float* bias2    = (float*)alloc(CDIM * 4);
  float* sumsq    = (float*)alloc(2 * EDIM * 4);

  hipMemsetAsync(sumsq, 0, 2 * EDIM * 4, stream);
  kinit<<<1176, 256, 0, stream>>>(dw_w, ln_w, ln_b, w1, b1, grn_b, w2, b2, Btab, w1p, b1f, bias2);
  kconv<<<3456, 384, 0, stream>>>(x, Btab, dw_b, y);
  ksum<<<3456, 512, 0, stream>>>(y, w1p, b1f, sumsq, anorm);
  kpackw2<<<36, 256, 0, stream>>>(sumsq, grn_w, w2, w2s);
  kfused<<<3456, 512, 0, stream>>>(anorm, w1p, b1f, w2s, bias2, x, out);
}

// Round 24
// 280.544 us; speedup vs baseline: 1.0533x; 1.0107x over previous
//
#include <hip/hip_runtime.h>
#include <hip/hip_bf16.h>
#include <string.h>

#define S3 110592  // 48^3
#define CDIM 96
#define EDIM 384
#define ZIN 14
#define YIN 22

typedef __attribute__((ext_vector_type(8))) short bf16x8;
typedef __attribute__((ext_vector_type(4))) float f32x4;
typedef unsigned short ushort_t;
typedef unsigned char uchar_t;

__device__ __forceinline__ ushort_t f2bf(float f) {
  __hip_bfloat16 h = __float2bfloat16(f);
  union { __hip_bfloat16 h; ushort_t u; } cv; cv.h = h; return cv.u;
}
__device__ __forceinline__ float bf2f(ushort_t u) {
  union { __hip_bfloat16 h; ushort_t u; } cv; cv.u = u; return __bfloat162float(cv.h);
}
// f32 -> fp8 e4m3 (OCP on gfx950), low byte of packed conversion
__device__ __forceinline__ uchar_t f2fp8(float f) {
  int r = __builtin_amdgcn_cvt_pk_fp8_f32(f, f, 0, false);
  return (uchar_t)(r & 0xff);
}
// tanh-form GELU in exp2/rcp form (log2e folded into constants)
__device__ __forceinline__ float gelu_fast(float v) {
  float t = v * v;
  float u = v * fmaf(-0.10294324f, t, -2.3022084f);
  float s = __builtin_amdgcn_exp2f(u);
  return v * __builtin_amdgcn_rcpf(1.f + s);
}

// ---------------------------------------------------------------- kinit: kpackB + kprep merged (independent prep, one launch)
__global__ void kinit(const float* __restrict__ dw_w,
                      const float* __restrict__ ln_w, const float* __restrict__ ln_b,
                      const float* __restrict__ w1, const float* __restrict__ b1,
                      const float* __restrict__ grn_b, const float* __restrict__ w2,
                      const float* __restrict__ b2,
                      ushort_t* __restrict__ Btab, ushort_t* __restrict__ w1p,
                      float* __restrict__ b1f, float* __restrict__ bias2) {
  int idx = blockIdx.x * 256 + threadIdx.x;
  // --- kpackB: SHIFTED Toeplitz B[k][n] = w[tz][ty][k-n-1], 8 outputs/thread, uint4 store
  {
    int base_i = idx * 8;  // grid sized exactly: base_i < 96*49*512
    int pos = base_i & 511; int t = (base_i >> 9) % 49; int c = base_i / (49 * 512);
    int lane = pos >> 3;
    int k0 = (lane >> 4) * 8, n = lane & 15;
    int tz = t / 7, ty = t % 7;
    const float* w = dw_w + c * 343 + tz * 49 + ty * 7;
    ushort_t tmp[8];
#pragma unroll
    for (int j = 0; j < 8; ++j) {
      int tx = k0 + j - n - 1;
      tmp[j] = (tx >= 0 && tx < 7) ? f2bf(w[tx]) : (ushort_t)0;
    }
    *(uint4*)&Btab[base_i] = *(uint4*)tmp;
  }
  // --- kprep: pack w1 (fold ln_w), b1f (fold ln_b), bias2 (fold grn_b via w2)
  if (idx < 24 * 3 * 64 * 8) {
    int j = idx & 7, lane = (idx >> 3) & 63, ks = (idx >> 9) % 3, nt = idx / 1536;
    int c = ks * 32 + (lane >> 4) * 8 + j;
    int e = nt * 16 + (lane & 15);
    w1p[idx] = f2bf(ln_w[c] * w1[c * EDIM + e]);
  }
  if (idx < EDIM) {
    float s = b1[idx];
    for (int c = 0; c < CDIM; ++c) s += ln_b[c] * w1[c * EDIM + idx];
    b1f[idx] = s;
  }
  if (idx < CDIM) {
    float s = b2[idx];
    for (int e = 0; e < EDIM; ++e) s += grn_b[e] * w2[e * CDIM + idx];
    bias2[idx] = s;
  }
}

// ---------------------------------------------------------------- depthwise conv MFMA compute (templated zl-half; all acc indices compile-time)
template<int HALF>
__device__ __forceinline__ void conv_ty_loop(const unsigned* tile, const ushort_t* Bt,
                                             int lane, int am, int xg, f32x4* acc) {
#pragma unroll 1
  for (int ty = 0; ty < 7; ++ty) {
    bf16x8 bfr[7];
#pragma unroll
    for (int tz = 0; tz < 7; ++tz)
      bfr[tz] = *(const bf16x8*)&Bt[(tz * 7 + ty) * 512 + lane * 8];  // L2-resident (XCD-affine)
    int rowbase = am + ty;
#pragma unroll
    for (int zl = 0; zl < 7; ++zl) {
      int row = (HALF * 7 + zl) * YIN + rowbase;
      int byteoff = (row << 7) + (xg ^ ((row & 7) << 4));
      bf16x8 af = *(const bf16x8*)((const char*)tile + byteoff);
#pragma unroll
      for (int tz = 0; tz < 7; ++tz) {
        int l = (HALF == 0) ? (zl - tz) : (zl + 6 - tz);
        if (l >= 0 && l < 7)  // compile-time after unroll
          acc[l] = __builtin_amdgcn_mfma_f32_16x16x32_bf16(af, bfr[tz], acc[l], 0, 0, 0);
      }
    }
  }
}

// ---------------------------------------------------------------- depthwise 7x7x7 conv on the MATRIX pipe
// 384 threads = 6 waves. Staging: register-prefetched (T14) — 2 batches of 10 clamped loads.
// XCD-affine bid (bid&7 = XCD): Btab slice + halos L2-resident.
__global__ __launch_bounds__(384, 6) void kconv(const float* __restrict__ x,
                                                const ushort_t* __restrict__ Btab,
                                                const float* __restrict__ dw_b,
                                                ushort_t* __restrict__ y) {
  __shared__ unsigned tile[ZIN * YIN * 32];
  int bid = blockIdx.x;                       // 3456 = 8 XCD * (12c * 2b * 6zt * 3yt)
  int xcd = bid & 7, wi = bid >> 3;           // wi in [0,432)
  int c = xcd * 12 + wi / 36;
  int rr_ = wi % 36;
  int b = rr_ / 18;
  int t_ = rr_ % 18;
  int zt = t_ / 3, yt = t_ % 3;
  int z0 = zt * 8, y0 = yt * 16;
  size_t base = (size_t)(b * 96 + c) * S3;
  int tid = threadIdx.x;

  // Phase A: zero edge pairs (pc 0,1,26..31) for all 308 rows
  for (int i = tid; i < 308 * 8; i += 384) {
    int row = i >> 3; int pe = i & 7;
    int pc = (pe < 2) ? pe : pe + 24;
    tile[(row << 5) + (pc ^ ((row & 7) << 2))] = 0u;
  }
  // Phase B: real pairs pc=2..25 (x = 2pc-4, 2pc-3 in [0,48)), register-prefetched
  {
    const float* xb = x + base;
#pragma unroll
    for (int hb = 0; hb < 2; ++hb) {
      float2 pv[10];
#pragma unroll
      for (int k = 0; k < 10; ++k) {
        int i = tid + (hb * 10 + k) * 384;
        i = (i < 7392) ? i : 7391;            // ragged tail -> duplicate benign
        int row = i / 24; int pc = 2 + (i - row * 24);
        int dz = row / YIN, dy = row - dz * YIN;
        int gz = z0 - 3 + dz, gy = y0 - 3 + dy;
        int cz = min(max(gz, 0), 47), cy = min(max(gy, 0), 47);
        pv[k] = *(const float2*)&xb[(size_t)cz * 2304 + cy * 48 + 2 * pc - 4];
      }
#pragma unroll
      for (int k = 0; k < 10; ++k) {
        int i = tid + (hb * 10 + k) * 384;
        i = (i < 7392) ? i : 7391;
        int row = i / 24; int pc = 2 + (i - row * 24);
        int dz = row / YIN, dy = row - dz * YIN;
        int gz = z0 - 3 + dz, gy = y0 - 3 + dy;
        bool ok = ((unsigned)gz < 48u) && ((unsigned)gy < 48u);
        float v0 = ok ? pv[k].x : 0.f;
        float v1 = ok ? pv[k].y : 0.f;
        tile[(row << 5) + (pc ^ ((row & 7) << 2))] = (unsigned)f2bf(v0) | ((unsigned)f2bf(v1) << 16);
      }
    }
  }
  __syncthreads();

  int w = tid >> 6;
  int X = w % 3, half = w / 3;
  int lane = tid & 63;
  int am = lane & 15, g = lane >> 4;
  int xg = X * 32 + g * 16;  // byte offset of k-window within row (before swizzle)

  f32x4 acc[7];
#pragma unroll
  for (int p = 0; p < 7; ++p) acc[p] = (f32x4){0.f, 0.f, 0.f, 0.f};

  const ushort_t* __restrict__ Bt = Btab + (size_t)c * 49 * 512;
  if (half == 0) conv_ty_loop<0>(tile, Bt, lane, am, xg, acc);
  else           conv_ty_loop<1>(tile, Bt, lane, am, xg, acc);

  float bv = dw_b[c];
  float* red = (float*)tile;
  int rcol = X * 16 + am;
  __syncthreads();  // all tile reads done -> reuse as f32 scratch
  if (half == 0) {
#pragma unroll
    for (int l = 1; l < 7; ++l)
#pragma unroll
      for (int r = 0; r < 4; ++r)
        red[(l - 1) * 800 + (g * 4 + r) * 50 + rcol] = acc[l][r];
  }
  __syncthreads();
  if (half == 0) {
    size_t zb = base + (size_t)z0 * 2304;
#pragma unroll
    for (int r = 0; r < 4; ++r)
      y[zb + (size_t)(y0 + g * 4 + r) * 48 + rcol] = f2bf(acc[0][r] + bv);
  } else {
#pragma unroll
    for (int l = 0; l < 7; ++l) {
      size_t zb = base + (size_t)(z0 + l + 1) * 2304;
#pragma unroll
      for (int r = 0; r < 4; ++r) {
        float v = acc[l][r] + bv;
        if (l < 6) v += red[l * 800 + (g * 4 + r) * 50 + rcol];
        y[zb + (size_t)(y0 + g * 4 + r) * 48 + rcol] = f2bf(v);
      }
    }
  }
}

// ---------------------------------------------------------------- pass 1: LN + GEMM1 + GELU -> sumsq + anorm (normalized y, bf16, [pos][96])
__global__ __launch_bounds__(512, 4) void ksum(const ushort_t* __restrict__ y,
                                               const ushort_t* __restrict__ w1p,
                                               const float* __restrict__ b1f,
                                               float* __restrict__ sumsq,
                                               ushort_t* __restrict__ anorm) {
  __shared__ ushort_t Al[64 * 104];
  __shared__ float red_s[8][64], red_q[8][64];
  __shared__ float stat_mu[64], stat_rv[64];
  __shared__ float ssq_s[EDIM];
  int tid = threadIdx.x;
  int q = tid >> 6, lane = tid & 63;
  size_t pos0 = (size_t)blockIdx.x * 64;
  int b = (int)(pos0 / S3);
  int sp0 = (int)(pos0 % S3);

  bf16x8 bfg[3][3];
#pragma unroll
  for (int ntl = 0; ntl < 3; ++ntl)
#pragma unroll
    for (int ks = 0; ks < 3; ++ks)
      bfg[ntl][ks] = *(const bf16x8*)&w1p[(size_t)(((q * 3 + ntl) * 3 + ks) * 64 + lane) * 8];

  float v[12];
  float s = 0.f, ss = 0.f;
  const ushort_t* yb = y + (size_t)b * 96 * S3 + sp0 + lane;
#pragma unroll
  for (int i = 0; i < 12; ++i) {
    float f = bf2f(yb[(size_t)(q * 12 + i) * S3]);
    v[i] = f; s += f; ss += f * f;
  }
  red_s[q][lane] = s; red_q[q][lane] = ss;
  __syncthreads();
  if (tid < 64) {
    float su = 0.f, sq = 0.f;
#pragma unroll
    for (int k = 0; k < 8; ++k) { su += red_s[k][tid]; sq += red_q[k][tid]; }
    float mu = su * (1.f / 96.f);
    float var = sq * (1.f / 96.f) - mu * mu;
    stat_mu[tid] = mu;
    stat_rv[tid] = rsqrtf(var + 1e-6f);
  }
  __syncthreads();
  {
    float mu = stat_mu[lane], rv = stat_rv[lane];
#pragma unroll
    for (int i4 = 0; i4 < 3; ++i4) {
      ushort_t u0 = f2bf((v[i4 * 4 + 0] - mu) * rv);
      ushort_t u1 = f2bf((v[i4 * 4 + 1] - mu) * rv);
      ushort_t u2 = f2bf((v[i4 * 4 + 2] - mu) * rv);
      ushort_t u3 = f2bf((v[i4 * 4 + 3] - mu) * rv);
      uint2 t; t.x = (unsigned)u0 | ((unsigned)u1 << 16); t.y = (unsigned)u2 | ((unsigned)u3 << 16);
      *(uint2*)&Al[lane * 104 + q * 12 + i4 * 4] = t;
    }
  }
  __syncthreads();

  // export normalized tile: [pos][96] bf16, 12 uint4 per position row
  {
    uint4* dst = (uint4*)(anorm + pos0 * 96);
    for (int i = tid; i < 64 * 12; i += 512) {
      int p = i / 12, j = i - p * 12;
      dst[p * 12 + j] = *(const uint4*)&Al[p * 104 + j * 8];
    }
  }

  f32x4 acc[4][3];
#pragma unroll
  for (int mt = 0; mt < 4; ++mt)
#pragma unroll
    for (int ntl = 0; ntl < 3; ++ntl) acc[mt][ntl] = (f32x4){0.f, 0.f, 0.f, 0.f};

  int row = lane & 15, g = lane >> 4;
#pragma unroll
  for (int ks = 0; ks < 3; ++ks) {
    bf16x8 af[4];
    int colb = ks * 32 + g * 8;
#pragma unroll
    for (int mt = 0; mt < 4; ++mt)
      af[mt] = *(const bf16x8*)&Al[(mt * 16 + row) * 104 + colb];
#pragma unroll
    for (int ntl = 0; ntl < 3; ++ntl) {
#pragma unroll
      for (int mt = 0; mt < 4; ++mt)
        acc[mt][ntl] = __builtin_amdgcn_mfma_f32_16x16x32_bf16(af[mt], bfg[ntl][ks], acc[mt][ntl], 0, 0, 0);
    }
  }

#pragma unroll
  for (int ntl = 0; ntl < 3; ++ntl) {
    int e = q * 48 + ntl * 16 + row;
    float bb = b1f[e];
    float ssq = 0.f;
#pragma unroll
    for (int mt = 0; mt < 4; ++mt) {
#pragma unroll
      for (int r = 0; r < 4; ++r) {
        float gel = gelu_fast(acc[mt][ntl][r] + bb);
        ssq += gel * gel;
      }
    }
    ssq += __shfl_xor(ssq, 16, 64);
    ssq += __shfl_xor(ssq, 32, 64);
    if (g == 0) ssq_s[e] = ssq;
  }
  __syncthreads();
  if (tid < EDIM) atomicAdd(&sumsq[b * EDIM + tid], ssq_s[tid]);
}

// ---------------------------------------------------------------- kpackw2 (kscale folded in): per-batch GRN scale + fp8 pack of scale*w2
__global__ void kpackw2(const float* __restrict__ sumsq, const float* __restrict__ grn_w,
                        const float* __restrict__ w2, uchar_t* __restrict__ w2s) {
  __shared__ float redw[4];
  __shared__ float mean_s;
  int tid = threadIdx.x;
  int idx = blockIdx.x * 256 + tid;  // exactly 9216
  int b = idx / 4608;
  // block-local GRN mean over 384 channels
  float p = sqrtf(sumsq[b * EDIM + tid]);
  if (tid < 128) p += sqrtf(sumsq[b * EDIM + 256 + tid]);
#pragma unroll
  for (int off = 1; off <= 32; off <<= 1) p += __shfl_xor(p, off, 64);
  if ((tid & 63) == 0) redw[tid >> 6] = p;
  __syncthreads();
  if (tid == 0) mean_s = (redw[0] + redw[1] + redw[2] + redw[3]) * (1.f / EDIM);
  __syncthreads();
  float inv = 1.f / (mean_s + 1e-6f);

  int lane = idx & 63;
  int ks = (idx >> 6) % 12;
  int nt = ((idx >> 6) / 12) % 6;
  int cc = nt * 16 + (lane & 15);
  float sw[8];
#pragma unroll
  for (int j = 0; j < 8; ++j) {
    int e = ks * 32 + (lane >> 4) * 8 + j;
    float sc = grn_w[e] * (sqrtf(sumsq[b * EDIM + e]) * inv) + 1.f;
    sw[j] = sc * w2[e * CDIM + cc];
  }
  unsigned r0 = (unsigned)__builtin_amdgcn_cvt_pk_fp8_f32(sw[0], sw[1], 0, false);
  r0 = (unsigned)__builtin_amdgcn_cvt_pk_fp8_f32(sw[2], sw[3], (int)r0, true);
  unsigned r1 = (unsigned)__builtin_amdgcn_cvt_pk_fp8_f32(sw[4], sw[5], 0, false);
  r1 = (unsigned)__builtin_amdgcn_cvt_pk_fp8_f32(sw[6], sw[7], (int)r1, true);
  *(uint2*)&w2s[(size_t)((b * 72 + nt * 12 + ks) * 64 + lane) * 8] = make_uint2(r0, r1);
}

// ---------------------------------------------------------------- pass 2 FUSED (64 pos/block):
// GEMM1(anorm, bf16) -> GELU -> fp8 LDS h-tile [64][400] -> GEMM2(fp8) -> +x, direct store.
// x residual prefetched at kernel start (T14): HBM latency hidden under GEMM1+GELU+GEMM2.
__global__ __launch_bounds__(512, 6) void kfused(const ushort_t* __restrict__ anorm,
                                                 const ushort_t* __restrict__ w1p,
                                                 const float* __restrict__ b1f,
                                                 const uchar_t* __restrict__ w2s,
                                                 const float* __restrict__ bias2,
                                                 const float* __restrict__ x,
                                                 float* __restrict__ out) {
  __shared__ __align__(16) uchar_t htile[64 * 400];

  int tid = threadIdx.x;
  int q = tid >> 6, lane = tid & 63;
  size_t pos0 = (size_t)blockIdx.x * 64;
  int b = (int)(pos0 / S3);
  int sp0 = (int)(pos0 % S3);
  int row = lane & 15, g = lane >> 4;
  int mt2 = q & 3, nh = q >> 2;

  // ---- early x prefetch + bias2 (consumed after GEMM2; latency hidden under compute)
  f32x4 xv[3];
  float bb2[3];
#pragma unroll
  for (int ntl = 0; ntl < 3; ++ntl) {
    int cc = (nh * 3 + ntl) * 16 + row;
    xv[ntl] = *(const f32x4*)&x[(size_t)(b * 96 + cc) * S3 + sp0 + mt2 * 16 + g * 4];
    bb2[ntl] = bias2[cc];
  }

  // ---- GEMM1: A direct from anorm (bf16), wave q -> e-range [q*48, +48)
  f32x4 acc[4][3];
#pragma unroll
  for (int mt = 0; mt < 4; ++mt)
#pragma unroll
    for (int ntl = 0; ntl < 3; ++ntl) acc[mt][ntl] = (f32x4){0.f, 0.f, 0.f, 0.f};

  const ushort_t* ab = anorm + pos0 * 96;
#pragma unroll
  for (int ks = 0; ks < 3; ++ks) {
    int colb = ks * 32 + g * 8;
    bf16x8 af[4];
#pragma unroll
    for (int mt = 0; mt < 4; ++mt)
      af[mt] = *(const bf16x8*)&ab[(mt * 16 + row) * 96 + colb];
#pragma unroll
    for (int ntl = 0; ntl < 3; ++ntl) {
      bf16x8 bfg = *(const bf16x8*)&w1p[(size_t)(((q * 3 + ntl) * 3 + ks) * 64 + lane) * 8];
#pragma unroll
      for (int mt = 0; mt < 4; ++mt)
        acc[mt][ntl] = __builtin_amdgcn_mfma_f32_16x16x32_bf16(af[mt], bfg, acc[mt][ntl], 0, 0, 0);
    }
  }

  // ---- GELU -> fp8 LDS h-tile [p][e], row stride 400 B
#pragma unroll
  for (int ntl = 0; ntl < 3; ++ntl) {
    int e = q * 48 + ntl * 16 + row;
    float bb = b1f[e];
#pragma unroll
    for (int mt = 0; mt < 4; ++mt) {
#pragma unroll
      for (int r = 0; r < 4; ++r) {
        float gel = gelu_fast(acc[mt][ntl][r] + bb);
        htile[(mt * 16 + g * 4 + r) * 400 + e] = f2fp8(gel);
      }
    }
  }
  __syncthreads();

  // ---- GEMM2 (fp8): wave q -> m-tile (q&3), c-half (q>>2)
  f32x4 acc2[3];
#pragma unroll
  for (int ntl = 0; ntl < 3; ++ntl) acc2[ntl] = (f32x4){0.f, 0.f, 0.f, 0.f};
  const uchar_t* w2b = w2s + (size_t)b * 36864;
  const uchar_t* arow = &htile[(mt2 * 16 + row) * 400];
#pragma unroll
  for (int ks = 0; ks < 12; ++ks) {
    long af8 = *(const long*)&arow[g * 8 + ks * 32];
#pragma unroll
    for (int ntl = 0; ntl < 3; ++ntl) {
      int nt = nh * 3 + ntl;
      long bf8 = *(const long*)&w2b[(size_t)((nt * 12 + ks) * 64 + lane) * 8];
      acc2[ntl] = __builtin_amdgcn_mfma_f32_16x16x32_fp8_fp8(af8, bf8, acc2[ntl], 0, 0, 0);
    }
  }

  // ---- direct store: out = acc2 + bias2 + x (position-contiguous float4 per lane)
#pragma unroll
  for (int ntl = 0; ntl < 3; ++ntl) {
    int cc = (nh * 3 + ntl) * 16 + row;
    f32x4 ov;
#pragma unroll
    for (int r = 0; r < 4; ++r) ov[r] = acc2[ntl][r] + bb2[ntl] + xv[ntl][r];
    *(f32x4*)&out[(size_t)(b * 96 + cc) * S3 + sp0 + mt2 * 16 + g * 4] = ov;
  }
}

// ----------------------------------------------------------------
extern "C" void kernel_launch(void* const* d_in, const int* in_sizes, int n_in,
                              void* d_out, int out_size, void* d_ws, size_t ws_size,
                              hipStream_t stream) {
  const float* x     = (const float*)d_in[0];
  const float* dw_w  = (const float*)d_in[1];
  const float* dw_b  = (const float*)d_in[2];
  const float* ln_w  = (const float*)d_in[3];
  const float* ln_b  = (const float*)d_in[4];
  const float* w1    = (const float*)d_in[5];
  const float* b1    = (const float*)d_in[6];
  const float* grn_w = (const float*)d_in[7];
  const float* grn_b = (const float*)d_in[8];
  const float* w2    = (const float*)d_in[9];
  const float* b2    = (const float*)d_in[10];
  float* out = (float*)d_out;

  char* ws = (char*)d_ws;
  size_t off = 0;
  auto alloc = [&](size_t bytes) -> void* {
    void* p = ws + off;
    off = (off + bytes + 511) & ~(size_t)511;
    return p;
  };
  ushort_t* y     = (ushort_t*)alloc((size_t)2 * 96 * S3 * 2);       // 42.5 MB bf16 conv out
  ushort_t* anorm = (ushort_t*)alloc((size_t)221184 * 96 * 2);       // 42.5 MB normalized bf16
  ushort_t* w1p   = (ushort_t*)alloc(36864 * 2);
  uchar_t* w2s    = (uchar_t*)alloc((size_t)2 * 36864);              // fp8 scale-folded w2
  ushort_t* Btab  = (ushort_t*)alloc((size_t)96 * 49 * 512 * 2);     // 4.8 MB Toeplitz B-frags
  float* b1f      = (float*)alloc(EDIM * 4);
  float* bias2    = (float*)alloc(CDIM * 4);
  float* sumsq    = (float*)alloc(2 * EDIM * 4);

  hipMemsetAsync(sumsq, 0, 2 * EDIM * 4, stream);
  kinit<<<1176, 256, 0, stream>>>(dw_w, ln_w, ln_b, w1, b1, grn_b, w2, b2, Btab, w1p, b1f, bias2);
  kconv<<<3456, 384, 0, stream>>>(x, Btab, dw_b, y);
  ksum<<<3456, 512, 0, stream>>>(y, w1p, b1f, sumsq, anorm);
  kpackw2<<<36, 256, 0, stream>>>(sumsq, grn_w, w2, w2s);
  kfused<<<3456, 512, 0, stream>>>(anorm, w1p, b1f, w2s, bias2, x, out);
}